// Round 12
// baseline (463.070 us; speedup 1.0000x reference)
//
#include <hip/hip_runtime.h>
#include <hip/hip_bf16.h>
#include <math.h>

// ---------------------------------------------------------------------------
// LongNetViT forward, split-kernel (31 dispatches), bf16 MFMA, fragment-major
// layouts. r12 changes:
//  - LN fused into QKV/MLP1 GEMMs: they read the full row anyway, so row
//    mean/var computed inline from the A-loads (per-lane sum + 2 shfl_xor)
//    and fragments normalized on the fly. ln kernel + hnbf buffer deleted
//    (-8 dispatches, -4MB/layer traffic, zero redundant compute).
//  - h stored FRAG-MAJOR f32 (hf) so fused A-loads stay dense; writers
//    (patch/proj/mlp2) were scatter-writers already (pattern improves).
// ---------------------------------------------------------------------------

typedef __attribute__((ext_vector_type(8))) short short8;
typedef __attribute__((ext_vector_type(4))) float f32x4;

__device__ __forceinline__ unsigned short f2bf(float x) {
  unsigned u = __float_as_uint(x);
  u += 0x7FFF + ((u >> 16) & 1);
  return (unsigned short)(u >> 16);
}
__device__ __forceinline__ float bf2f(unsigned short s) {
  return __uint_as_float(((unsigned)s) << 16);
}

// ---------------------------------------------------------------------------
// Prep: bid<3456 weight transpose -> frag-major wt; else x f32 -> frag xb.
// ---------------------------------------------------------------------------
__global__ __launch_bounds__(256) void prep_kernel(
    const float* __restrict__ pw, const float* __restrict__ wqkv,
    const float* __restrict__ wo, const float* __restrict__ w1,
    const float* __restrict__ w2, unsigned short* __restrict__ wt,
    const float* __restrict__ x, unsigned short* __restrict__ xb) {
  __shared__ float T[32][33];
  if (blockIdx.x >= 3456) {
    const int i = (blockIdx.x - 3456) * 256 + threadIdx.x;  // 786432 total
    const int row = i / 192, k8 = i % 192;
    const int k = k8 * 8;
    size_t dst = ((size_t)(row >> 4) * 48 + (k >> 5)) * 512 +
                 (size_t)(row & 15) * 32 + (k & 31);
    if (row >= 4095) {
      *(uint4*)(xb + dst) = make_uint4(0, 0, 0, 0);
      return;
    }
    const float4 a = *(const float4*)(x + (size_t)row * 1536 + k);
    const float4 b = *(const float4*)(x + (size_t)row * 1536 + k + 4);
    unsigned u0 = (unsigned)f2bf(a.x) | ((unsigned)f2bf(a.y) << 16);
    unsigned u1 = (unsigned)f2bf(a.z) | ((unsigned)f2bf(a.w) << 16);
    unsigned u2 = (unsigned)f2bf(b.x) | ((unsigned)f2bf(b.y) << 16);
    unsigned u3 = (unsigned)f2bf(b.z) | ((unsigned)f2bf(b.w) << 16);
    *(uint4*)(xb + dst) = make_uint4(u0, u1, u2, u3);
    return;
  }
  const int bid = blockIdx.x;
  const float* src;
  int Kd, Nd, lt;
  size_t doff;
  if (bid < 384) {
    src = pw; Kd = 1536; Nd = 256; doff = 0; lt = bid;
  } else if (bid < 1152) {
    int l = (bid - 384) / 192, r = (bid - 384) % 192;
    src = wqkv + (size_t)l * 196608; Kd = 256; Nd = 768;
    doff = 393216 + (size_t)l * 196608; lt = r;
  } else if (bid < 1408) {
    int l = (bid - 1152) / 64, r = (bid - 1152) % 64;
    src = wo + (size_t)l * 65536; Kd = 256; Nd = 256;
    doff = 1179648 + (size_t)l * 65536; lt = r;
  } else if (bid < 2432) {
    int l = (bid - 1408) / 256, r = (bid - 1408) % 256;
    src = w1 + (size_t)l * 262144; Kd = 256; Nd = 1024;
    doff = 1441792 + (size_t)l * 262144; lt = r;
  } else {
    int l = (bid - 2432) / 256, r = (bid - 2432) % 256;
    src = w2 + (size_t)l * 262144; Kd = 1024; Nd = 256;
    doff = 2490368 + (size_t)l * 262144; lt = r;
  }
  const int tilesK = Kd >> 5;
  const int tn = lt / tilesK, tk = lt % tilesK;
  const int k0 = tk * 32, n0 = tn * 32;
  const int t = threadIdx.x;
  const int rr = t >> 3, c4 = t & 7;
  float4 v = *(const float4*)(src + (size_t)(k0 + rr) * Nd + n0 + c4 * 4);
  T[rr][c4 * 4 + 0] = v.x;
  T[rr][c4 * 4 + 1] = v.y;
  T[rr][c4 * 4 + 2] = v.z;
  T[rr][c4 * 4 + 3] = v.w;
  __syncthreads();
  float o0 = T[c4 * 4 + 0][rr], o1 = T[c4 * 4 + 1][rr];
  float o2 = T[c4 * 4 + 2][rr], o3 = T[c4 * 4 + 3][rr];
  unsigned u0 = (unsigned)f2bf(o0) | ((unsigned)f2bf(o1) << 16);
  unsigned u1 = (unsigned)f2bf(o2) | ((unsigned)f2bf(o3) << 16);
  const int n = n0 + rr;
  size_t fo = doff + ((size_t)(n >> 4) * (Kd >> 5) + (k0 >> 5)) * 512 +
              (size_t)(n & 15) * 32 + c4 * 4;
  *(uint2*)(wt + fo) = make_uint2(u0, u1);
}

// ---------------------------------------------------------------------------
// Patch embed GEMM -> hf (frag-major f32). grid (64,8).
// ---------------------------------------------------------------------------
__global__ __launch_bounds__(256) void gemm_patch(
    const unsigned short* __restrict__ Af, const unsigned short* __restrict__ Bt,
    const float* __restrict__ bias, const float* __restrict__ coords,
    const float* __restrict__ cls, const float* __restrict__ pe,
    float* __restrict__ hf) {
  const int lane = threadIdx.x & 63, w = threadIdx.x >> 6;
  const int g = lane >> 4, q = lane & 15;
  const int bm = blockIdx.x * 64, bn = blockIdx.y * 32;

  const unsigned short* ap =
      Af + ((size_t)((bm >> 4) + w) * 48) * 512 + q * 32 + 8 * g;
  const unsigned short* bp = Bt + q * 32 + 8 * g;

  f32x4 acc[2];
#pragma unroll
  for (int i = 0; i < 2; i++) acc[i] = (f32x4){0.f, 0.f, 0.f, 0.f};

#pragma unroll 4
  for (int ks = 0; ks < 48; ks++) {
    short8 af = *(const short8*)(ap + (size_t)ks * 512);
#pragma unroll
    for (int cf = 0; cf < 2; cf++) {
      short8 bf = *(const short8*)(bp +
          ((size_t)(((bn >> 4) + cf) * 48 + ks)) * 512);
      acc[cf] = __builtin_amdgcn_mfma_f32_16x16x32_bf16(af, bf, acc[cf], 0, 0, 0);
    }
  }

  const int orow0 = bm + 16 * w + 4 * g;
  int prow[4];
#pragma unroll
  for (int rg = 0; rg < 4; rg++) {
    int orow = orow0 + rg;
    orow = orow < 4095 ? orow : 4094;
    float c0 = coords[(size_t)orow * 2 + 0];
    float c1 = coords[(size_t)orow * 2 + 1];
    prow[rg] = (int)floorf(c0 * (1.f / 256.f)) * 512 +
               (int)floorf(c1 * (1.f / 256.f)) + 1;
  }
#pragma unroll
  for (int cf = 0; cf < 2; cf++) {
    const int col = bn + 16 * cf + q;
    const float bs = bias[col];
#pragma unroll
    for (int rg = 0; rg < 4; rg++) {
      int orow = orow0 + rg;
      if (orow < 4095) {
        float c = acc[cf][rg] + bs + pe[(size_t)prow[rg] * 256 + col];
        int row = orow + 1;
        size_t fo = ((size_t)(row >> 4) * 8 + (col >> 5)) * 512 +
                    (size_t)(row & 15) * 32 + (col & 31);
        hf[fo] = c;
      }
    }
  }
  if (blockIdx.x == 0 && blockIdx.y == 0 && threadIdx.x < 64) {
    float4 cv = *(const float4*)(cls + threadIdx.x * 4);
    float4 pv = *(const float4*)(pe + threadIdx.x * 4);
    size_t fo = (size_t)(threadIdx.x >> 3) * 512 + (threadIdx.x & 7) * 4;
    *(float4*)(hf + fo) =
        make_float4(cv.x + pv.x, cv.y + pv.y, cv.z + pv.z, cv.w + pv.w);
  }
}

// ---------------------------------------------------------------------------
// Fused LN + GEMM: A = hf frag-major f32 (Kd=256); row stats computed inline
// from the A-loads (per-lane 64-elem sums + 2 shfl across g-lanes).
// EPI 3: row-major bf16 out (qkv). EPI 1: GELU -> frag-major bf16 (mlp1).
// ---------------------------------------------------------------------------
template <int EPI>
__global__ __launch_bounds__(256) void gemm_lnA(
    const float* __restrict__ Hf, const unsigned short* __restrict__ Bt,
    const float* __restrict__ lnw, const float* __restrict__ lnb,
    const float* __restrict__ bias, unsigned short* __restrict__ Cv, int N) {
  const int lane = threadIdx.x & 63, w = threadIdx.x >> 6;
  const int g = lane >> 4, q = lane & 15;
  const int bm = blockIdx.x * 64, bn = blockIdx.y * 64;
  const float* ap = Hf + ((size_t)((bm >> 4) + w) * 8) * 512 + q * 32 + 8 * g;
  const unsigned short* bp = Bt + q * 32 + 8 * g;

  // pass 1: load row fragments (row q of this row-tile), accumulate stats
  float a[8][8];
  float s1 = 0.f, s2 = 0.f;
#pragma unroll
  for (int ks = 0; ks < 8; ks++) {
    float4 u = *(const float4*)(ap + (size_t)ks * 512);
    float4 v = *(const float4*)(ap + (size_t)ks * 512 + 4);
    a[ks][0] = u.x; a[ks][1] = u.y; a[ks][2] = u.z; a[ks][3] = u.w;
    a[ks][4] = v.x; a[ks][5] = v.y; a[ks][6] = v.z; a[ks][7] = v.w;
#pragma unroll
    for (int j = 0; j < 8; j++) {
      s1 += a[ks][j];
      s2 += a[ks][j] * a[ks][j];
    }
  }
  s1 += __shfl_xor(s1, 16); s1 += __shfl_xor(s1, 32);
  s2 += __shfl_xor(s2, 16); s2 += __shfl_xor(s2, 32);
  const float mu = s1 * (1.f / 256.f);
  const float inv = rsqrtf(s2 * (1.f / 256.f) - mu * mu + 1e-5f);

  f32x4 acc[4];
#pragma unroll
  for (int i = 0; i < 4; i++) acc[i] = (f32x4){0.f, 0.f, 0.f, 0.f};

#pragma unroll
  for (int ks = 0; ks < 8; ks++) {
    float4 wv0 = *(const float4*)(lnw + 32 * ks + 8 * g);
    float4 wv1 = *(const float4*)(lnw + 32 * ks + 8 * g + 4);
    float4 bv0 = *(const float4*)(lnb + 32 * ks + 8 * g);
    float4 bv1 = *(const float4*)(lnb + 32 * ks + 8 * g + 4);
    float n0 = (a[ks][0] - mu) * inv * wv0.x + bv0.x;
    float n1 = (a[ks][1] - mu) * inv * wv0.y + bv0.y;
    float n2 = (a[ks][2] - mu) * inv * wv0.z + bv0.z;
    float n3 = (a[ks][3] - mu) * inv * wv0.w + bv0.w;
    float n4 = (a[ks][4] - mu) * inv * wv1.x + bv1.x;
    float n5 = (a[ks][5] - mu) * inv * wv1.y + bv1.y;
    float n6 = (a[ks][6] - mu) * inv * wv1.z + bv1.z;
    float n7 = (a[ks][7] - mu) * inv * wv1.w + bv1.w;
    union { unsigned u[4]; short8 v; } af;
    af.u[0] = (unsigned)f2bf(n0) | ((unsigned)f2bf(n1) << 16);
    af.u[1] = (unsigned)f2bf(n2) | ((unsigned)f2bf(n3) << 16);
    af.u[2] = (unsigned)f2bf(n4) | ((unsigned)f2bf(n5) << 16);
    af.u[3] = (unsigned)f2bf(n6) | ((unsigned)f2bf(n7) << 16);
#pragma unroll
    for (int cf = 0; cf < 4; cf++) {
      short8 bf = *(const short8*)(bp +
          ((size_t)((bn >> 4) + cf) * 8 + ks) * 512);
      acc[cf] = __builtin_amdgcn_mfma_f32_16x16x32_bf16(af.v, bf, acc[cf], 0, 0, 0);
    }
  }

  const int orow0 = bm + 16 * w + 4 * g;
#pragma unroll
  for (int cf = 0; cf < 4; cf++) {
    const int col = bn + 16 * cf + q;
    const float bs = bias[col];
#pragma unroll
    for (int rg = 0; rg < 4; rg++) {
      float c = acc[cf][rg] + bs;
      const int orow = orow0 + rg;
      if (EPI == 1) {
        c = 0.5f * c * (1.f + erff(c * 0.70710678118654752f));
        const int cq = 16 * cf + q;
        size_t idx = ((size_t)(orow >> 4) * (N >> 5) + (bn >> 5) + (cq >> 5)) *
                         512 +
                     (size_t)(orow & 15) * 32 + (cq & 31);
        Cv[idx] = f2bf(c);
      } else {
        Cv[(size_t)orow * N + col] = f2bf(c);
      }
    }
  }
}

// ---------------------------------------------------------------------------
// Proj GEMM: A = attb frag (Kd=256), B frag, grid (64,8), += into hf.
// ---------------------------------------------------------------------------
__global__ __launch_bounds__(256) void gemm_proj(
    const unsigned short* __restrict__ Af, const unsigned short* __restrict__ Bt,
    const float* __restrict__ bias, float* __restrict__ hf) {
  const int lane = threadIdx.x & 63, w = threadIdx.x >> 6;
  const int g = lane >> 4, q = lane & 15;
  const int bm = blockIdx.x * 64, bn = blockIdx.y * 32;
  const unsigned short* ap =
      Af + ((size_t)((bm >> 4) + w) * 8) * 512 + q * 32 + 8 * g;
  const unsigned short* bp = Bt + q * 32 + 8 * g;

  f32x4 acc[2];
#pragma unroll
  for (int i = 0; i < 2; i++) acc[i] = (f32x4){0.f, 0.f, 0.f, 0.f};

#pragma unroll
  for (int ks = 0; ks < 8; ks++) {
    short8 af = *(const short8*)(ap + (size_t)ks * 512);
#pragma unroll
    for (int cf = 0; cf < 2; cf++) {
      short8 bf = *(const short8*)(bp +
          ((size_t)((bn >> 4) + cf) * 8 + ks) * 512);
      acc[cf] = __builtin_amdgcn_mfma_f32_16x16x32_bf16(af, bf, acc[cf], 0, 0, 0);
    }
  }

  const int orow0 = bm + 16 * w + 4 * g;
#pragma unroll
  for (int cf = 0; cf < 2; cf++) {
    const int col = bn + 16 * cf + q;
    const float bs = bias[col];
#pragma unroll
    for (int rg = 0; rg < 4; rg++) {
      int row = orow0 + rg;
      size_t fo = ((size_t)(row >> 4) * 8 + (col >> 5)) * 512 +
                  (size_t)(row & 15) * 32 + (col & 31);
      hf[fo] += acc[cf][rg] + bs;
    }
  }
}

// ---------------------------------------------------------------------------
// MLP2 GEMM: A = midb frag (Kd=1024), B frag, grid (64,8), += into hf.
// ---------------------------------------------------------------------------
__global__ __launch_bounds__(256) void gemm_mlp2(
    const unsigned short* __restrict__ Af, const unsigned short* __restrict__ Bt,
    const float* __restrict__ bias, float* __restrict__ hf) {
  const int lane = threadIdx.x & 63, w = threadIdx.x >> 6;
  const int g = lane >> 4, q = lane & 15;
  const int bm = blockIdx.x * 64, bn = blockIdx.y * 32;
  const unsigned short* ap =
      Af + ((size_t)((bm >> 4) + w) * 32) * 512 + q * 32 + 8 * g;
  const unsigned short* bp = Bt + q * 32 + 8 * g;

  f32x4 acc[2];
#pragma unroll
  for (int i = 0; i < 2; i++) acc[i] = (f32x4){0.f, 0.f, 0.f, 0.f};

#pragma unroll 4
  for (int ks = 0; ks < 32; ks++) {
    short8 af = *(const short8*)(ap + (size_t)ks * 512);
#pragma unroll
    for (int cf = 0; cf < 2; cf++) {
      short8 bf = *(const short8*)(bp +
          ((size_t)((bn >> 4) + cf) * 32 + ks) * 512);
      acc[cf] = __builtin_amdgcn_mfma_f32_16x16x32_bf16(af, bf, acc[cf], 0, 0, 0);
    }
  }

  const int orow0 = bm + 16 * w + 4 * g;
#pragma unroll
  for (int cf = 0; cf < 2; cf++) {
    const int col = bn + 16 * cf + q;
    const float bs = bias[col];
#pragma unroll
    for (int rg = 0; rg < 4; rg++) {
      int row = orow0 + rg;
      size_t fo = ((size_t)(row >> 4) * 8 + (col >> 5)) * 512 +
                  (size_t)(row & 15) * 32 + (col & 31);
      hf[fo] += acc[cf][rg] + bs;
    }
  }
}

// ---------------------------------------------------------------------------
// Gather (XCD-swizzled decode kept from r11 — neutral, harmless).
// ---------------------------------------------------------------------------
__device__ __forceinline__ void decode_gather(int bid, int& r, int& m,
                                              int& off, int& base, int& h,
                                              int& kt, int& ub) {
  const int c = bid & 7;
  const int j = bid >> 3;  // 0..123
  if (j < 64) {
    int u = c + 8 * (j >> 4);
    kt = j & 15;
    r = 1; m = 1024; base = (u >> 3) * 1024; h = u & 7; off = 0; ub = u * 32768;
  } else if (j < 96) {
    int jj = j - 64;
    int grp = c + 8 * (jj >> 4);
    h = grp >> 1;
    kt = (grp & 1) * 16 + (jj & 15);
    r = 2; m = 2048; base = 0; off = h & 1; ub = 1048576 + h * 65536;
  } else if (j < 112) {
    h = c; kt = j - 96;
    r = 4; m = 1024; base = 0; off = h & 3; ub = 1572864 + h * 32768;
  } else if (j < 120) {
    h = c; kt = j - 112;
    r = 8; m = 512; base = 0; off = h & 7; ub = 1835008 + h * 16384;
  } else {
    h = c; kt = j - 120;
    r = 16; m = 256; base = 0; off = h; ub = 1966080 + h * 8192;
  }
}

__global__ __launch_bounds__(256) void gather_kernel(
    const unsigned short* __restrict__ qkvb, unsigned short* __restrict__ kg,
    unsigned short* __restrict__ vt) {
  __shared__ unsigned short T[32][64];
  int r, m, off, base, h, kt, ub;
  decode_gather(blockIdx.x, r, m, off, base, h, kt, ub);
  const int t = threadIdx.x;
  {
    int key = t >> 2, c = t & 3;
    size_t row = base + off + (size_t)r * (kt * 64 + key);
    const unsigned short* src = qkvb + row * 768 + h * 32 + 8 * c;
    short8 kk = *(const short8*)(src + 256);
    int gk = kt * 64 + key;
    *(short8*)(kg + ub + (size_t)(gk >> 4) * 512 + (size_t)(gk & 15) * 32 +
               8 * c) = kk;
    short8 vv = *(const short8*)(src + 512);
#pragma unroll
    for (int i = 0; i < 8; i++) T[8 * c + i][key] = (unsigned short)vv[i];
  }
  __syncthreads();
  int dim = t >> 3, c8 = t & 7;
  int vk = kt * 64 + 8 * c8;
  *(short8*)(vt + ub + ((size_t)(vk >> 5) * 2 + (dim >> 4)) * 512 +
             (size_t)(dim & 15) * 32 + (vk & 31)) = *(const short8*)&T[dim][8 * c8];
}

// ---------------------------------------------------------------------------
// Attention decode (XCD-swizzled, r11).
// ---------------------------------------------------------------------------
__device__ __forceinline__ void decode_attn(int bid, int& slot, int& r, int& m,
                                            int& nt, int& koff, int& off,
                                            int& base, int& h, int& qt,
                                            int& ub) {
  const int c = bid & 7;
  const int j = bid >> 3;  // 0..155
  if (j < 64) {
    int u = c + 8 * (j >> 4);
    qt = j & 15;
    slot = 0; r = 1; m = 1024; nt = 16; koff = 0;
    base = (u >> 3) * 1024; h = u & 7; off = 0; ub = u * 32768;
  } else if (j < 128) {
    int jj = j - 64;
    int grp = c + 8 * (jj >> 5);
    h = grp >> 1;
    int half = grp & 1;
    qt = jj & 31;
    slot = 1 + half; r = 2; m = 2048; nt = 16; koff = half * 1024;
    base = 0; off = h & 1; ub = 1048576 + h * 65536;
  } else if (j < 144) {
    h = c; qt = j - 128;
    slot = 3; r = 4; m = 1024; nt = 16; koff = 0;
    base = 0; off = h & 3; ub = 1572864 + h * 32768;
  } else if (j < 152) {
    h = c; qt = j - 144;
    slot = 4; r = 8; m = 512; nt = 8; koff = 0;
    base = 0; off = h & 7; ub = 1835008 + h * 16384;
  } else {
    h = c; qt = j - 152;
    slot = 5; r = 16; m = 256; nt = 4; koff = 0;
    base = 0; off = h; ub = 1966080 + h * 8192;
  }
}

// ---------------------------------------------------------------------------
// bf16 MFMA flash attention (max-free softmax, frag-major K/V).
// ---------------------------------------------------------------------------
__global__ __launch_bounds__(256) void attn_mfma_kernel(
    const unsigned short* __restrict__ qkvb,
    const unsigned short* __restrict__ kg, const unsigned short* __restrict__ vt,
    unsigned short* __restrict__ oa, float* __restrict__ lse_all) {
  int slot, r, m, nt, koff, off, base, h, qt, ub;
  decode_attn(blockIdx.x, slot, r, m, nt, koff, off, base, h, qt, ub);

  const int lane = threadIdx.x & 63;
  const int wid = threadIdx.x >> 6;
  const int g = lane >> 4, q = lane & 15;
  const int q0 = qt * 64 + wid * 16;

  const size_t qrow = base + off + (size_t)r * (q0 + q);
  short8 qf = *(const short8*)(qkvb + qrow * 768 + h * 32 + 8 * g);

  const unsigned short* kp = kg + ub + q * 32 + 8 * g;
  const unsigned short* vp = vt + ub + q * 32 + 8 * g;
  const int kt0 = koff >> 4;
  const int vt0 = koff >> 5;

  f32x4 ot0 = {0.f, 0.f, 0.f, 0.f}, ot1 = {0.f, 0.f, 0.f, 0.f};
  float rl = 0.f;
  const float scale = 0.17677669529663687f;

  short8 kf[4];
#pragma unroll
  for (int a = 0; a < 4; a++)
    kf[a] = *(const short8*)(kp + (size_t)(kt0 + a) * 512);

  for (int kt = 0; kt < nt; ++kt) {
    const int k0 = kt * 64;
    const int v2 = vt0 + (k0 >> 5);
    short8 va0 = *(const short8*)(vp + (size_t)(v2 * 2 + 0) * 512);
    short8 vb0 = *(const short8*)(vp + (size_t)(v2 * 2 + 1) * 512);
    short8 va1 = *(const short8*)(vp + (size_t)((v2 + 1) * 2 + 0) * 512);
    short8 vb1 = *(const short8*)(vp + (size_t)((v2 + 1) * 2 + 1) * 512);

    f32x4 st[4];
#pragma unroll
    for (int a = 0; a < 4; a++) {
      f32x4 z = {0.f, 0.f, 0.f, 0.f};
      st[a] = __builtin_amdgcn_mfma_f32_16x16x32_bf16(kf[a], qf, z, 0, 0, 0);
    }
    if (kt + 1 < nt) {
#pragma unroll
      for (int a = 0; a < 4; a++)
        kf[a] = *(const short8*)(kp + (size_t)(kt0 + ((k0 + 64) >> 4) + a) * 512);
    }

    float p[4][4];
    float tl = 0.f;
#pragma unroll
    for (int a = 0; a < 4; a++)
#pragma unroll
      for (int rr = 0; rr < 4; rr++) {
        p[a][rr] = __expf(st[a][rr] * scale);
        tl += p[a][rr];
      }
    tl += __shfl_xor(tl, 16);
    tl += __shfl_xor(tl, 32);
    rl += tl;

    unsigned pk[4][2];
#pragma unroll
    for (int a = 0; a < 4; a++) {
      asm("v_cvt_pk_bf16_f32 %0, %1, %2"
          : "=v"(pk[a][0]) : "v"(p[a][0]), "v"(p[a][1]));
      asm("v_cvt_pk_bf16_f32 %0, %1, %2"
          : "=v"(pk[a][1]) : "v"(p[a][2]), "v"(p[a][3]));
    }

#pragma unroll
    for (int kk = 0; kk < 2; kk++) {
      union { unsigned w[4]; short8 v; } pb;
#pragma unroll
      for (int jj = 0; jj < 2; jj++) {
        int src = q + 16 * ((2 * g + jj) & 3);
#pragma unroll
        for (int d = 0; d < 2; d++) {
          unsigned lo = (unsigned)__shfl((int)pk[2 * kk + 0][d], src);
          unsigned hi = (unsigned)__shfl((int)pk[2 * kk + 1][d], src);
          pb.w[jj * 2 + d] = (g >> 1) ? hi : lo;
        }
      }
      if (kk == 0) {
        ot0 = __builtin_amdgcn_mfma_f32_16x16x32_bf16(va0, pb.v, ot0, 0, 0, 0);
        ot1 = __builtin_amdgcn_mfma_f32_16x16x32_bf16(vb0, pb.v, ot1, 0, 0, 0);
      } else {
        ot0 = __builtin_amdgcn_mfma_f32_16x16x32_bf16(va1, pb.v, ot0, 0, 0, 0);
        ot1 = __builtin_amdgcn_mfma_f32_16x16x32_bf16(vb1, pb.v, ot1, 0, 0, 0);
      }
    }
  }

  float inv = 1.f / rl;
  int pos = base + off + r * (q0 + q);
  size_t ob = (((size_t)(slot * 256 + (pos >> 4)) * 8 + h) * 16 + (pos & 15)) * 32;
  unsigned w0 = (unsigned)f2bf(ot0[0] * inv) | ((unsigned)f2bf(ot0[1] * inv) << 16);
  unsigned w1 = (unsigned)f2bf(ot0[2] * inv) | ((unsigned)f2bf(ot0[3] * inv) << 16);
  unsigned w2 = (unsigned)f2bf(ot1[0] * inv) | ((unsigned)f2bf(ot1[1] * inv) << 16);
  unsigned w3 = (unsigned)f2bf(ot1[2] * inv) | ((unsigned)f2bf(ot1[3] * inv) << 16);
  *(uint2*)(oa + ob + 4 * g) = make_uint2(w0, w1);
  *(uint2*)(oa + ob + 16 + 4 * g) = make_uint2(w2, w3);
  if (g == 0)
    lse_all[((size_t)slot * 4096 + pos) * 8 + h] = __logf(rl);
}

// ---------------------------------------------------------------------------
// Combine 6 slots per (pos, head) by LSE softmax -> attb frag-major bf16.
// ---------------------------------------------------------------------------
__global__ __launch_bounds__(256) void combine_kernel(
    const unsigned short* __restrict__ oa, const float* __restrict__ lse_all,
    unsigned short* __restrict__ attb) {
  const int pt = blockIdx.x >> 3, ph = blockIdx.x & 7;
  const int t = threadIdx.x;
  const int d0 = (t & 15) * 2;
  const int pl = t >> 4;
  const int pos = pt * 16 + pl;

  const int msk[6] = {0, 1, 1, 3, 7, 15};
  float l[6];
  bool cov[6];
#pragma unroll
  for (int s = 0; s < 6; s++) {
    cov[s] = ((pos ^ ph) & msk[s]) == 0;
    l[s] = cov[s] ? lse_all[((size_t)s * 4096 + pos) * 8 + ph] : -3.0e38f;
  }
  float mx = l[0];
#pragma unroll
  for (int s = 1; s < 6; s++) mx = fmaxf(mx, l[s]);
  float wsum = 0.f, o0 = 0.f, o1 = 0.f;
#pragma unroll
  for (int s = 0; s < 6; s++) {
    if (cov[s]) {
      float wg = __expf(l[s] - mx);
      wsum += wg;
      unsigned u = *(const unsigned*)(oa +
          (((size_t)(s * 256 + pt) * 8 + ph) * 16 + pl) * 32 + d0);
      o0 += wg * bf2f((unsigned short)(u & 0xFFFF));
      o1 += wg * bf2f((unsigned short)(u >> 16));
    }
  }
  float inv = 1.f / wsum;
  unsigned u = (unsigned)f2bf(o0 * inv) | ((unsigned)f2bf(o1 * inv) << 16);
  *(unsigned*)(attb + ((size_t)pt * 8 + ph) * 512 + pl * 32 + d0) = u;
}

// ---------------------------------------------------------------------------
// Final: double-LN of hf row 0 (frag-major) -> out.
// ---------------------------------------------------------------------------
__global__ __launch_bounds__(64) void final_kernel(
    const float* __restrict__ hf, const float* __restrict__ ew,
    const float* __restrict__ eb, const float* __restrict__ nw,
    const float* __restrict__ nb, float* __restrict__ out) {
  const int lane = threadIdx.x;
  size_t fo = (size_t)(lane >> 3) * 512 + (lane & 7) * 4;
  float4 v = *(const float4*)(hf + fo);
  float s1 = v.x + v.y + v.z + v.w;
  float s2 = v.x * v.x + v.y * v.y + v.z * v.z + v.w * v.w;
#pragma unroll
  for (int o = 32; o; o >>= 1) {
    s1 += __shfl_xor(s1, o);
    s2 += __shfl_xor(s2, o);
  }
  float mu = s1 * (1.f / 256.f);
  float inv = rsqrtf(s2 * (1.f / 256.f) - mu * mu + 1e-5f);
  float4 wv = *(const float4*)(ew + lane * 4);
  float4 bv = *(const float4*)(eb + lane * 4);
  float4 tv;
  tv.x = (v.x - mu) * inv * wv.x + bv.x;
  tv.y = (v.y - mu) * inv * wv.y + bv.y;
  tv.z = (v.z - mu) * inv * wv.z + bv.z;
  tv.w = (v.w - mu) * inv * wv.w + bv.w;
  s1 = tv.x + tv.y + tv.z + tv.w;
  s2 = tv.x * tv.x + tv.y * tv.y + tv.z * tv.z + tv.w * tv.w;
#pragma unroll
  for (int o = 32; o; o >>= 1) {
    s1 += __shfl_xor(s1, o);
    s2 += __shfl_xor(s2, o);
  }
  mu = s1 * (1.f / 256.f);
  inv = rsqrtf(s2 * (1.f / 256.f) - mu * mu + 1e-5f);
  float4 w2v = *(const float4*)(nw + lane * 4);
  float4 b2v = *(const float4*)(nb + lane * 4);
  float4 o;
  o.x = (tv.x - mu) * inv * w2v.x + b2v.x;
  o.y = (tv.y - mu) * inv * w2v.y + b2v.y;
  o.z = (tv.z - mu) * inv * w2v.z + b2v.z;
  o.w = (tv.w - mu) * inv * w2v.w + b2v.w;
  *(float4*)(out + lane * 4) = o;
}

// ---------------------------------------------------------------------------

extern "C" void kernel_launch(void* const* d_in, const int* in_sizes, int n_in,
                              void* d_out, int out_size, void* d_ws,
                              size_t ws_size, hipStream_t stream) {
  const float* x      = (const float*)d_in[0];
  const float* coords = (const float*)d_in[1];
  const float* pw     = (const float*)d_in[2];
  const float* pb     = (const float*)d_in[3];
  const float* cls    = (const float*)d_in[4];
  const float* pe     = (const float*)d_in[5];
  const float* ln1w   = (const float*)d_in[6];
  const float* ln1b   = (const float*)d_in[7];
  const float* wqkv   = (const float*)d_in[8];
  const float* bqkv   = (const float*)d_in[9];
  const float* wo     = (const float*)d_in[10];
  const float* bo     = (const float*)d_in[11];
  const float* ln2w   = (const float*)d_in[12];
  const float* ln2b   = (const float*)d_in[13];
  const float* w1     = (const float*)d_in[14];
  const float* b1     = (const float*)d_in[15];
  const float* w2     = (const float*)d_in[16];
  const float* b2     = (const float*)d_in[17];
  const float* encw   = (const float*)d_in[18];
  const float* encb   = (const float*)d_in[19];
  const float* nw     = (const float*)d_in[20];
  const float* nb     = (const float*)d_in[21];

  float* ws = (float*)d_ws;
  float* hf             = ws;                                // 1,048,576 f32
  unsigned short* qkvb  = (unsigned short*)(ws + 1048576);   // 3,145,728 us
  unsigned short* kg    = (unsigned short*)(ws + 2621440);   // 2,031,616 us
  unsigned short* vt    = (unsigned short*)(ws + 3637248);   // 2,031,616 us
  unsigned short* oa    = (unsigned short*)(ws + 4653056);   // 6,291,456 us
  float* lse            = ws + 7798784;                      //   196,608 f32
  unsigned short* attb  = (unsigned short*)(ws + 7995392);   // 1,048,576 us
  unsigned short* midb  = (unsigned short*)(ws + 8519680);   // 4,194,304 us
  unsigned short* xb    = (unsigned short*)(ws + 10616832);  // 6,291,456 us
  unsigned short* wt    = (unsigned short*)(ws + 13762560);  // 3,538,944 us
  // ends at 15,532,032 f32 ~= 62.1 MiB

  prep_kernel<<<6528, 256, 0, stream>>>(pw, wqkv, wo, w1, w2, wt, x, xb);
  gemm_patch<<<dim3(64, 8), 256, 0, stream>>>(xb, wt, pb, coords, cls, pe, hf);

  for (int l = 0; l < 4; l++) {
    gemm_lnA<3><<<dim3(64, 12), 256, 0, stream>>>(
        hf, wt + 393216 + (size_t)l * 196608, ln1w + l * 256, ln1b + l * 256,
        bqkv + l * 768, qkvb, 768);
    gather_kernel<<<992, 256, 0, stream>>>(qkvb, kg, vt);
    attn_mfma_kernel<<<1248, 256, 0, stream>>>(qkvb, kg, vt, oa, lse);
    combine_kernel<<<2048, 256, 0, stream>>>(oa, lse, attb);
    gemm_proj<<<dim3(64, 8), 256, 0, stream>>>(
        attb, wt + 1179648 + (size_t)l * 65536, bo + l * 256, hf);
    gemm_lnA<1><<<dim3(64, 16), 256, 0, stream>>>(
        hf, wt + 1441792 + (size_t)l * 262144, ln2w + l * 256, ln2b + l * 256,
        b1 + l * 1024, midb, 1024);
    gemm_mlp2<<<dim3(64, 8), 256, 0, stream>>>(
        midb, wt + 2490368 + (size_t)l * 262144, b2 + l * 256, hf);
  }

  final_kernel<<<1, 64, 0, stream>>>(hf, encw, encb, nw, nb, (float*)d_out);
}